// Round 4
// baseline (858.590 us; speedup 1.0000x reference)
//
#include <hip/hip_runtime.h>
#include <cmath>

#define N_AG 2048
#define HID  2048
#define OBSD 1024
#define ACT  64
#define GATES (4*HID)   // 8192
#define KX    (2*HID)   // 4096, X row width = [inp | h]
#define PADW  33        // epilogue LDS patch row width (f32), +1 pad

typedef short s16x8 __attribute__((ext_vector_type(8)));
typedef short s16x4 __attribute__((ext_vector_type(4)));
typedef float f32x4 __attribute__((ext_vector_type(4)));

__device__ __forceinline__ unsigned short f2bf(float f) {
  union { float f; unsigned u; } v; v.f = f;
  return (unsigned short)((v.u + 0x7FFFu + ((v.u >> 16) & 1u)) >> 16);
}
__device__ __forceinline__ float sigm(float x) { return 1.0f / (1.0f + expf(-x)); }

// async global->LDS DMA, 16B per lane; LDS dest = wave-uniform base + lane*16
__device__ __forceinline__ void gload16(const unsigned short* g, unsigned short* l) {
  __builtin_amdgcn_global_load_lds(
      (const __attribute__((address_space(1))) void*)g,
      (__attribute__((address_space(3))) void*)l, 16, 0, 0);
}

// ---------------- bf16 MFMA GEMM, dbuf global_load_lds pipeline (one barrier/K-iter).
// C(MxN) = A(MxK,row) * B(NxK,row)^T.
// MODE 1: encoder. A=obs, B=enc_w. Epilogue: e=tanh(+bias) -> C(f32), X[:,0:H]=bf16(e),
//         X[:,H:2H]=0.
// MODE 2: LSTM-fused, TRANSPOSED. A=Wc interleaved (g'=u*4+gate, 8192xKX), B=X
//         (2048xKX). Tile rows = g' (gate in acc reg index!), cols = agents.
//         Epilogue does full LSTMCell pointwise: cell/h(f32), X h-half (bf16).
template <int MODE>
__global__ __launch_bounds__(256) void gemm_bt(
    const unsigned short* __restrict__ A, const unsigned short* __restrict__ B,
    int K, int lda, int ldb,
    float* __restrict__ C, int ldc,
    const float* __restrict__ bias, unsigned short* __restrict__ X,
    float* __restrict__ cell, float* __restrict__ hout, int first)
{
  __shared__ __align__(16) char smem[MODE == 2 ? (2 * 128 * PADW * 4) : 32768];
  unsigned short* As0 = (unsigned short*)smem;             // [2][128*32]
  unsigned short* Bs0 = (unsigned short*)(smem + 16384);   // [2][128*32]
  const int tid  = threadIdx.x;
  const int lane = tid & 63;
  const int wave = tid >> 6;
  const int wm = wave >> 1, wn = wave & 1;
  const int quad = lane >> 4, l16 = lane & 15;
  const long tileM = (long)blockIdx.y * 128;   // A rows (MODE2: g')
  const long tileN = (long)blockIdx.x * 128;   // B rows (MODE2: agents)

  // staging: wave owns rows [wave*32, wave*32+32), 2 issues x 16 rows;
  // lane -> row (lane>>2), 16B chunk (lane&3). LDS row-major stride 32.
  const int srow = lane >> 2;
  const int skc  = (lane & 3) * 8;
  const unsigned short* gA = &A[(tileM + wave * 32 + srow) * lda + skc];
  const unsigned short* gB = &B[(tileN + wave * 32 + srow) * ldb + skc];
  const int ldsOff = wave * 32 * 32;

  f32x4 acc[4][4] = {};
  const int nIt = K >> 5;

  gload16(gA, &As0[ldsOff]);
  gload16(gA + 16 * lda, &As0[ldsOff + 16 * 32]);
  gload16(gB, &Bs0[ldsOff]);
  gload16(gB + 16 * ldb, &Bs0[ldsOff + 16 * 32]);

  for (int i = 0; i < nIt; ++i) {
    __syncthreads();  // drains DMA(tile i) issued one MFMA-phase earlier
    const int cb = (i & 1) * 4096;
    if (i + 1 < nIt) {
      const int nb = ((i + 1) & 1) * 4096;
      const long ko = (long)(i + 1) * 32;
      gload16(gA + ko, &As0[nb + ldsOff]);
      gload16(gA + ko + 16 * lda, &As0[nb + ldsOff + 16 * 32]);
      gload16(gB + ko, &Bs0[nb + ldsOff]);
      gload16(gB + ko + 16 * ldb, &Bs0[nb + ldsOff + 16 * 32]);
    }
    s16x8 af[4], bfr[4];
#pragma unroll
    for (int ii = 0; ii < 4; ++ii)
      af[ii] = *(const s16x8*)&As0[cb + (wm * 64 + ii * 16 + l16) * 32 + quad * 8];
#pragma unroll
    for (int j = 0; j < 4; ++j)
      bfr[j] = *(const s16x8*)&Bs0[cb + (wn * 64 + j * 16 + l16) * 32 + quad * 8];
#pragma unroll
    for (int ii = 0; ii < 4; ++ii)
#pragma unroll
      for (int j = 0; j < 4; ++j)
        acc[ii][j] = __builtin_amdgcn_mfma_f32_16x16x32_bf16(af[ii], bfr[j], acc[ii][j], 0, 0, 0);
  }

  if (MODE == 1) {
    // C/D layout: col=lane&15, row=quad*4+reg [m89/m91]
#pragma unroll
    for (int i = 0; i < 4; ++i) {
      long r0 = tileM + wm * 64 + i * 16 + quad * 4;
#pragma unroll
      for (int j = 0; j < 4; ++j) {
        long col = tileN + wn * 64 + j * 16 + l16;
        float bv = bias[col];
#pragma unroll
        for (int r = 0; r < 4; ++r) {
          float ev = tanhf(acc[i][j][r] + bv);
          long row = r0 + r;
          C[row * ldc + col] = ev;
          X[row * KX + col] = f2bf(ev);
          X[row * KX + HID + col] = 0;
        }
      }
    }
  } else {
    // MODE 2: rows are g' = u*4+gate. For acc[i][j]: u_loc = wm*16+i*4+quad,
    // n_loc = wn*64+j*16+l16, and reg r = gate (i,f,g,o). Zero shuffles.
    float* LC = (float*)smem;                      // [128][PADW] cell patch
    float* LH = (float*)(smem + 128 * PADW * 4);   // [128][PADW] h patch
    const long ubase = (long)blockIdx.y * 32;
    const long nbase = tileN;

    __syncthreads();  // K-loop LDS reads complete; reuse smem
    if (!first) {     // stage old cell patch, coalesced (128B per n-row)
#pragma unroll
      for (int p = 0; p < 4; ++p) {
        int row = (tid >> 3) + p * 32;
        int ch  = (tid & 7) * 4;
        *(f32x4*)&LC[row * PADW + ch] =
            *(const f32x4*)&cell[(size_t)(nbase + row) * HID + ubase + ch];
      }
    }
    __syncthreads();
#pragma unroll
    for (int i = 0; i < 4; ++i) {
      int u_loc = wm * 16 + i * 4 + quad;
      f32x4 bv = *(const f32x4*)&bias[(ubase + u_loc) * 4];  // (bi,bf,bg,bo) combined
#pragma unroll
      for (int j = 0; j < 4; ++j) {
        int n_loc = wn * 64 + j * 16 + l16;
        f32x4 z = acc[i][j];
        float ig = sigm(z[0] + bv[0]);
        float fg = sigm(z[1] + bv[1]);
        float gg = tanhf(z[2] + bv[2]);
        float og = sigm(z[3] + bv[3]);
        float cold = first ? 0.f : LC[n_loc * PADW + u_loc];
        float cn = fg * cold + ig * gg;
        float hv = og * tanhf(cn);
        LC[n_loc * PADW + u_loc] = cn;   // same thread owns this slot: no race
        LH[n_loc * PADW + u_loc] = hv;
      }
    }
    __syncthreads();
    // coalesced stores: per n-row, 32 u = 128B (f32) / 64B (bf16)
#pragma unroll
    for (int p = 0; p < 4; ++p) {
      int row = (tid >> 3) + p * 32;
      int ch  = (tid & 7) * 4;
      size_t gb = (size_t)(nbase + row) * HID + ubase + ch;
      f32x4 cv = *(const f32x4*)&LC[row * PADW + ch];
      f32x4 hv = *(const f32x4*)&LH[row * PADW + ch];
      *(f32x4*)&cell[gb] = cv;
      *(f32x4*)&hout[gb] = hv;
      s16x4 xb;
#pragma unroll
      for (int c = 0; c < 4; ++c) xb[c] = (short)f2bf(hv[c]);
      *(s16x4*)&X[(size_t)(nbase + row) * KX + HID + ubase + ch] = xb;
    }
  }
}

// ---------------- f32 -> bf16 convert (vector x4)
__global__ void cvt4(const float* __restrict__ in, unsigned short* __restrict__ out, int n4) {
  int i = blockIdx.x * 256 + threadIdx.x;
  if (i >= n4) return;
  f32x4 v = ((const f32x4*)in)[i];
  s16x4 o;
  o[0] = (short)f2bf(v[0]); o[1] = (short)f2bf(v[1]);
  o[2] = (short)f2bf(v[2]); o[3] = (short)f2bf(v[3]);
  ((s16x4*)out)[i] = o;
}

// ---------------- build Wc interleaved: out row g'=u*4+t <- [w_ih|w_hh] row t*H+u
__global__ void build_wc(const float* __restrict__ w_ih, const float* __restrict__ w_hh,
                         unsigned short* __restrict__ wc) {
  int i = blockIdx.x * 256 + threadIdx.x;   // over GATES*KX/4 chunks
  int k4 = i & 1023;
  int gp = i >> 10;
  int u = gp >> 2, t = gp & 3;
  size_t srow = (size_t)t * HID + u;
  const float* src = (k4 < 512) ? (w_ih + srow * HID + k4 * 4)
                                : (w_hh + srow * HID + (k4 - 512) * 4);
  f32x4 v = *(const f32x4*)src;
  s16x4 o;
  o[0] = (short)f2bf(v[0]); o[1] = (short)f2bf(v[1]);
  o[2] = (short)f2bf(v[2]); o[3] = (short)f2bf(v[3]);
  *(s16x4*)&wc[(size_t)gp * KX + k4 * 4] = o;
}

// ---------------- combined bias, interleaved: bc[u*4+t] = b_ih[t*H+u]+b_hh[t*H+u]
__global__ void biasmix(const float* __restrict__ b_ih, const float* __restrict__ b_hh,
                        float* __restrict__ bc) {
  int i = blockIdx.x * 256 + threadIdx.x;
  if (i >= GATES) return;
  int u = i >> 2, t = i & 3;
  bc[i] = b_ih[t * HID + u] + b_hh[t * HID + u];
}

// ---------------- n_alive reduction
__global__ void nalive_k(const float* __restrict__ alive, float* __restrict__ nA) {
  __shared__ float red[256];
  float s = 0.f;
  for (int i = threadIdx.x; i < N_AG; i += 256) s += alive[i];
  red[threadIdx.x] = s;
  __syncthreads();
  for (int st = 128; st > 0; st >>= 1) {
    if (threadIdx.x < st) red[threadIdx.x] += red[threadIdx.x + st];
    __syncthreads();
  }
  if (threadIdx.x == 0) nA[0] = red[0];
}

// ---------------- column sum: S[hid] += sum_n alive[n]*h[n][hid]  (S pre-zeroed)
__global__ void colsum(const float* __restrict__ h, const float* __restrict__ alive,
                       float* __restrict__ S) {
  int hid = blockIdx.x * 256 + threadIdx.x;
  int r0 = blockIdx.y * 128;
  float s = 0.f;
  for (int n = r0; n < r0 + 128; ++n) s += alive[n] * h[(size_t)n * HID + hid];
  atomicAdd(&S[hid], s);
}

// ---------------- comm + inp: X inp-half = bf16(e + alive_i*(S - alive_i*h)/(nA-1))
__global__ void inp_k(const float* __restrict__ e, const float* __restrict__ h,
                      const float* __restrict__ S, const float* __restrict__ alive,
                      const float* __restrict__ nA, unsigned short* __restrict__ X) {
  int i = blockIdx.x * 256 + threadIdx.x;  // over 1M
  int n = i >> 9;
  int hid = (i & 511) * 4;
  f32x4 ev = ((const f32x4*)e)[i];
  f32x4 hv = ((const f32x4*)h)[i];
  f32x4 Sv = *(const f32x4*)&S[hid];
  float al = alive[n];
  float inv = al / (nA[0] - 1.0f);
  s16x4 xb;
#pragma unroll
  for (int c = 0; c < 4; ++c) {
    float x = ev[c] + (Sv[c] - al * hv[c]) * inv;
    xb[c] = (short)f2bf(x);
  }
  *(s16x4*)&X[(size_t)n * KX + hid] = xb;
}

// ---------------- head: log_softmax(h@act_w^T + act_b) and h@val_w^T + val_b
__global__ __launch_bounds__(64) void head_k(const float* __restrict__ h,
                                             const float* __restrict__ act_w,
                                             const float* __restrict__ act_b,
                                             const float* __restrict__ val_w,
                                             const float* __restrict__ val_b,
                                             float* __restrict__ out) {
  __shared__ float hrow[HID];
  int n = blockIdx.x, t = threadIdx.x;  // 1 wave
  const float* hr = h + (size_t)n * HID;
  for (int k = t; k < HID; k += 64) hrow[k] = hr[k];
  __syncthreads();
  const float* aw = act_w + (size_t)t * HID;
  float acc = act_b[t];
  for (int k = 0; k < HID; k += 4) {
    f32x4 a = *(const f32x4*)&aw[k];
    f32x4 hh = *(const f32x4*)&hrow[k];
    acc += a[0] * hh[0] + a[1] * hh[1] + a[2] * hh[2] + a[3] * hh[3];
  }
  float m = acc;
  for (int off = 32; off; off >>= 1) m = fmaxf(m, __shfl_xor(m, off));
  float ex = expf(acc - m), s = ex;
  for (int off = 32; off; off >>= 1) s += __shfl_xor(s, off);
  out[(size_t)n * ACT + t] = acc - m - logf(s);
  float vp = 0.f;
  for (int k = t; k < HID; k += 64) vp += hrow[k] * val_w[k];
  for (int off = 32; off; off >>= 1) vp += __shfl_xor(vp, off);
  if (t == 0) out[(size_t)N_AG * ACT + n] = vp + val_b[0];
}

extern "C" void kernel_launch(void* const* d_in, const int* in_sizes, int n_in,
                              void* d_out, int out_size, void* d_ws, size_t ws_size,
                              hipStream_t stream) {
  const float* obs   = (const float*)d_in[0];
  const float* alive = (const float*)d_in[1];
  const float* enc_w = (const float*)d_in[2];
  const float* enc_b = (const float*)d_in[3];
  // d_in[4] g_w, d_in[5] g_b unused: gate = ceil(sigmoid(.)) == 1 identically
  const float* w_ih  = (const float*)d_in[6];
  const float* w_hh  = (const float*)d_in[7];
  const float* b_ih  = (const float*)d_in[8];
  const float* b_hh  = (const float*)d_in[9];
  const float* act_w = (const float*)d_in[10];
  const float* act_b = (const float*)d_in[11];
  const float* val_w = (const float*)d_in[12];
  const float* val_b = (const float*)d_in[13];
  float* out = (float*)d_out;

  char* p = (char*)d_ws;
  unsigned short* Wc   = (unsigned short*)p; p += (size_t)GATES * KX * 2;   // 64 MB
  unsigned short* X    = (unsigned short*)p; p += (size_t)N_AG * KX * 2;    // 16 MB
  unsigned short* obsb = (unsigned short*)p; p += (size_t)N_AG * OBSD * 2;  // 4 MB
  unsigned short* encb = (unsigned short*)p; p += (size_t)HID * OBSD * 2;   // 4 MB
  float* e    = (float*)p; p += (size_t)N_AG * HID * 4;                     // 16 MB
  float* h    = (float*)p; p += (size_t)N_AG * HID * 4;
  float* cell = (float*)p; p += (size_t)N_AG * HID * 4;
  float* bc   = (float*)p; p += GATES * 4;
  float* S    = (float*)p; p += 2048 * 4;
  float* nA   = (float*)p; p += 256;

  cvt4<<<(N_AG * OBSD / 4 + 255) / 256, 256, 0, stream>>>(obs, obsb, N_AG * OBSD / 4);
  cvt4<<<(HID * OBSD / 4 + 255) / 256, 256, 0, stream>>>(enc_w, encb, HID * OBSD / 4);
  build_wc<<<(GATES * KX / 4) / 256, 256, 0, stream>>>(w_ih, w_hh, Wc);
  biasmix<<<GATES / 256, 256, 0, stream>>>(b_ih, b_hh, bc);
  nalive_k<<<1, 256, 0, stream>>>(alive, nA);

  // encoder: e = tanh(obs @ enc_w^T + b), fills X inp-half + zeroes h-half
  gemm_bt<1><<<dim3(HID / 128, N_AG / 128), 256, 0, stream>>>(
      obsb, encb, OBSD, OBSD, OBSD, e, HID, enc_b, X, nullptr, nullptr, 0);

  for (int it = 0; it < 3; ++it) {
    if (it > 0) {
      hipMemsetAsync(S, 0, 2048 * 4, stream);
      colsum<<<dim3(HID / 256, 16), 256, 0, stream>>>(h, alive, S);
      inp_k<<<(N_AG * HID / 4) / 256, 256, 0, stream>>>(e, h, S, alive, nA, X);
    }
    // z^T = Wc @ X^T with LSTM fused in epilogue; iter0: K=HID (h==0)
    int K = (it == 0) ? HID : KX;
    gemm_bt<2><<<dim3(N_AG / 128, GATES / 128), 256, 0, stream>>>(
        Wc, X, K, KX, KX, nullptr, 0, bc, X, cell, h, it == 0);
  }

  head_k<<<N_AG, 64, 0, stream>>>(h, act_w, act_b, val_w, val_b, out);
}